// Round 17
// baseline (1162.384 us; speedup 1.0000x reference)
//
#include <hip/hip_runtime.h>
#include <hip/hip_bf16.h>

typedef __attribute__((ext_vector_type(8))) short bf16x8;
typedef __attribute__((ext_vector_type(4))) float f32x4;
typedef __attribute__((ext_vector_type(16))) float f32x16;
typedef unsigned short u16;
typedef unsigned int u32;

#define DT_ (10.0f / 9.0f)

__device__ __forceinline__ u16 f2bf(float f) {
  u32 u = __float_as_uint(f);
  u = (u + 0x7FFFu + ((u >> 16) & 1u)) >> 16;
  return (u16)u;
}

// Packed RNE f32x2 -> bf16x2 (one v_cvt_pk_bf16_f32).
__device__ __forceinline__ u32 cvtpk(float lo, float hi) {
  __hip_bfloat162 h = __float22bfloat162_rn(float2{lo, hi});
  return *reinterpret_cast<u32*>(&h);
}

__device__ __forceinline__ float tanh_fast(float x) {
  float ax = fabsf(x);
  float e = __expf(-2.0f * ax);
  float t = (1.0f - e) * __builtin_amdgcn_rcpf(1.0f + e);
  return copysignf(t, x);
}

// 32x32x16 A/B fragment from LDS: row/col = lane&31, k-chunk = (lane>>5)*8.
// Row-major [rows][K], row stride strideB bytes, XOR-swizzled ((r&7)<<4).
__device__ __forceinline__ bf16x8 frag_lds32(const u16* Mb, int row0, int kE, int strideB) {
  const int l = threadIdx.x & 63;
  const int r = row0 + (l & 31);
  const int kb = (kE + ((l >> 5) << 3)) << 1;
  const int off = r * strideB + (kb ^ ((r & 7) << 4));
  return *(const bf16x8*)((const char*)Mb + off);
}

// B-operand fragment straight from global W^T (row-major [N][K], bf16).
__device__ __forceinline__ bf16x8 frag_glb32(const u16* WT, int col0, int kE, int K) {
  const int l = threadIdx.x & 63;
  const int j = col0 + (l & 31);
  const int k = kE + ((l >> 5) << 3);
  return *(const bf16x8*)(WT + j * K + k);
}

// 64x64 wave-tile pass: 2x2 tiles of 32x32, K-step 16, 2-deep software pipeline.
// Outer loop unroll-1 (R11 lesson: full unroll hoists all loads and spills).
template <int KST, bool BLDS>
__device__ __forceinline__ void gemm32(f32x16 (&acc)[2][2], const u16* Ab, int aStrideB, int mb,
                                       const u16* Bp, int bK, int nb) {
#pragma unroll
  for (int mt = 0; mt < 2; ++mt)
#pragma unroll
    for (int nt = 0; nt < 2; ++nt)
#pragma unroll
      for (int e = 0; e < 16; ++e) acc[mt][nt][e] = 0.f;
  bf16x8 av0[2], bv0[2], av1[2], bv1[2];
#pragma unroll
  for (int nt = 0; nt < 2; ++nt) {
    if constexpr (BLDS) bv0[nt] = frag_lds32(Bp, nb + nt * 32, 0, 256);
    else                bv0[nt] = frag_glb32(Bp, nb + nt * 32, 0, bK);
  }
#pragma unroll
  for (int mt = 0; mt < 2; ++mt) av0[mt] = frag_lds32(Ab, mb + mt * 32, 0, aStrideB);
#pragma unroll 1
  for (int ks = 0; ks < KST; ks += 2) {
    const int k1 = (ks + 1) * 16;
#pragma unroll
    for (int nt = 0; nt < 2; ++nt) {
      if constexpr (BLDS) bv1[nt] = frag_lds32(Bp, nb + nt * 32, k1, 256);
      else                bv1[nt] = frag_glb32(Bp, nb + nt * 32, k1, bK);
    }
#pragma unroll
    for (int mt = 0; mt < 2; ++mt) av1[mt] = frag_lds32(Ab, mb + mt * 32, k1, aStrideB);
#pragma unroll
    for (int nt = 0; nt < 2; ++nt)
#pragma unroll
      for (int mt = 0; mt < 2; ++mt)
        acc[mt][nt] = __builtin_amdgcn_mfma_f32_32x32x16_bf16(av0[mt], bv0[nt], acc[mt][nt], 0, 0, 0);
    if (ks + 2 < KST) {
      const int k2 = (ks + 2) * 16;
#pragma unroll
      for (int nt = 0; nt < 2; ++nt) {
        if constexpr (BLDS) bv0[nt] = frag_lds32(Bp, nb + nt * 32, k2, 256);
        else                bv0[nt] = frag_glb32(Bp, nb + nt * 32, k2, bK);
      }
#pragma unroll
      for (int mt = 0; mt < 2; ++mt) av0[mt] = frag_lds32(Ab, mb + mt * 32, k2, aStrideB);
    }
#pragma unroll
    for (int nt = 0; nt < 2; ++nt)
#pragma unroll
      for (int mt = 0; mt < 2; ++mt)
        acc[mt][nt] = __builtin_amdgcn_mfma_f32_32x32x16_bf16(av1[mt], bv1[nt], acc[mt][nt], 0, 0, 0);
  }
}

// 64x32 wave-tile pass (stages 5/6): 2x1 tiles of 32x32.
template <int KST, bool BLDS>
__device__ __forceinline__ void gemm32n1(f32x16 (&acc)[2], const u16* Ab, int aStrideB, int mb,
                                         const u16* Bp, int bK, int nb) {
#pragma unroll
  for (int mt = 0; mt < 2; ++mt)
#pragma unroll
    for (int e = 0; e < 16; ++e) acc[mt][e] = 0.f;
  bf16x8 av0[2], av1[2];
  bf16x8 bv0, bv1;
  if constexpr (BLDS) bv0 = frag_lds32(Bp, nb, 0, 256);
  else                bv0 = frag_glb32(Bp, nb, 0, bK);
#pragma unroll
  for (int mt = 0; mt < 2; ++mt) av0[mt] = frag_lds32(Ab, mb + mt * 32, 0, aStrideB);
#pragma unroll 1
  for (int ks = 0; ks < KST; ks += 2) {
    const int k1 = (ks + 1) * 16;
    if constexpr (BLDS) bv1 = frag_lds32(Bp, nb, k1, 256);
    else                bv1 = frag_glb32(Bp, nb, k1, bK);
#pragma unroll
    for (int mt = 0; mt < 2; ++mt) av1[mt] = frag_lds32(Ab, mb + mt * 32, k1, aStrideB);
#pragma unroll
    for (int mt = 0; mt < 2; ++mt)
      acc[mt] = __builtin_amdgcn_mfma_f32_32x32x16_bf16(av0[mt], bv0, acc[mt], 0, 0, 0);
    if (ks + 2 < KST) {
      const int k2 = (ks + 2) * 16;
      if constexpr (BLDS) bv0 = frag_lds32(Bp, nb, k2, 256);
      else                bv0 = frag_glb32(Bp, nb, k2, bK);
#pragma unroll
      for (int mt = 0; mt < 2; ++mt) av0[mt] = frag_lds32(Ab, mb + mt * 32, k2, aStrideB);
    }
#pragma unroll
    for (int mt = 0; mt < 2; ++mt)
      acc[mt] = __builtin_amdgcn_mfma_f32_32x32x16_bf16(av1[mt], bv1, acc[mt], 0, 0, 0);
  }
}

// D-layout 32x32 (m74/m101): col = lane&31, row = (reg&3) + 8*(reg>>2) + 4*(lane>>5).
// Write t^T into Q [col][node] stride 256B: reg-quad = 4 consecutive rows -> uint2.
__device__ __forceinline__ void epi_T32(const f32x16 (&acc)[2][2], u16* Q, int nb, int mb, int lane) {
  const int l31 = lane & 31, lh = lane >> 5;
#pragma unroll
  for (int nt = 0; nt < 2; ++nt) {
    const int c = nb + nt * 32 + l31;
    const int swz = (c & 7) << 4;
    char* rowp = (char*)Q + c * 256;
#pragma unroll
    for (int mt = 0; mt < 2; ++mt)
#pragma unroll
      for (int q = 0; q < 4; ++q) {
        const int r0 = mb + mt * 32 + (lh << 2) + (q << 3);
        uint2 pk;
        pk.x = cvtpk(acc[mt][nt][4 * q + 0], acc[mt][nt][4 * q + 1]);
        pk.y = cvtpk(acc[mt][nt][4 * q + 2], acc[mt][nt][4 * q + 3]);
        *(uint2*)(rowp + ((r0 << 1) ^ swz)) = pk;
      }
  }
}

__device__ __forceinline__ void epi_T32n1(const f32x16 (&acc)[2], u16* Q, int nb, int mb, int lane) {
  const int l31 = lane & 31, lh = lane >> 5;
  const int c = nb + l31;
  const int swz = (c & 7) << 4;
  char* rowp = (char*)Q + c * 256;
#pragma unroll
  for (int mt = 0; mt < 2; ++mt)
#pragma unroll
    for (int q = 0; q < 4; ++q) {
      const int r0 = mb + mt * 32 + (lh << 2) + (q << 3);
      uint2 pk;
      pk.x = cvtpk(acc[mt][4 * q + 0], acc[mt][4 * q + 1]);
      pk.y = cvtpk(acc[mt][4 * q + 2], acc[mt][4 * q + 3]);
      *(uint2*)(rowp + ((r0 << 1) ^ swz)) = pk;
    }
}

// Bias + tanh + node-major P write (stride 512B, swizzled), scalar u16 stores.
__device__ __forceinline__ void epi_H32(const f32x16 (&acc)[2][2], u16* P, const float* __restrict__ b,
                                        int nb, int mb, int lane) {
  const int l31 = lane & 31, lh = lane >> 5;
#pragma unroll
  for (int nt = 0; nt < 2; ++nt) {
    const int c = nb + nt * 32 + l31;
    const float bb = b[c];
    const int csh = c << 1;
#pragma unroll
    for (int mt = 0; mt < 2; ++mt)
#pragma unroll
      for (int q = 0; q < 4; ++q) {
        const int r0 = mb + mt * 32 + (lh << 2) + (q << 3);
        float t0 = tanh_fast(acc[mt][nt][4 * q + 0] + bb);
        float t1 = tanh_fast(acc[mt][nt][4 * q + 1] + bb);
        float t2 = tanh_fast(acc[mt][nt][4 * q + 2] + bb);
        float t3 = tanh_fast(acc[mt][nt][4 * q + 3] + bb);
        const u32 p01 = cvtpk(t0, t1);
        const u32 p23 = cvtpk(t2, t3);
        *(u16*)((char*)P + (r0 + 0) * 512 + (csh ^ (((r0 + 0) & 7) << 4))) = (u16)p01;
        *(u16*)((char*)P + (r0 + 1) * 512 + (csh ^ (((r0 + 1) & 7) << 4))) = (u16)(p01 >> 16);
        *(u16*)((char*)P + (r0 + 2) * 512 + (csh ^ (((r0 + 2) & 7) << 4))) = (u16)p23;
        *(u16*)((char*)P + (r0 + 3) * 512 + (csh ^ (((r0 + 3) & 7) << 4))) = (u16)(p23 >> 16);
      }
  }
}

// One f(z) evaluation; z (bf16, node-major, stride 256B, swizzled) in P on entry.
// ZERO persistent register state. RK state in ws slabs:
//   SA: y -> V -> W -> yn      SB: k1 -> U
template <int E>
__device__ __forceinline__ void feval(int step,
    u16* P, u16* Q, const u16* As,
    const u16* __restrict__ W1T, const u16* __restrict__ W2T, const u16* __restrict__ W3T,
    const float* __restrict__ b1, const float* __restrict__ b2, const float* __restrict__ b3,
    f32x4* __restrict__ SA, f32x4* __restrict__ SB,
    float* __restrict__ out,
    int batch, int tid, int lane, int mb, int wn) {
  const int l31 = lane & 31, lh = lane >> 5;

  { // stage 1: t1 = z @ W1   [M128 N256 K128] -> Q (t^T)
    f32x16 acc[2][2];
    gemm32<8, false>(acc, P, 256, mb, W1T, 128, wn * 64);
    epi_T32(acc, Q, wn * 64, mb, lane);
  }
  __syncthreads();
  { // stage 2: h1 = tanh(A @ t1 + b1) -> P node-major (stride 512)
    f32x16 acc[2][2];
    gemm32<8, true>(acc, As, 256, mb, Q, 0, wn * 64);
    epi_H32(acc, P, b1, wn * 64, mb, lane);
  }
  __syncthreads();
  { // stage 3: t2 = h1 @ W2  [M128 N256 K256] -> Q (t^T)
    f32x16 acc[2][2];
    gemm32<16, false>(acc, P, 512, mb, W2T, 256, wn * 64);
    epi_T32(acc, Q, wn * 64, mb, lane);
  }
  __syncthreads();
  { // stage 4: h2 = tanh(A @ t2 + b2) -> P node-major
    f32x16 acc[2][2];
    gemm32<8, true>(acc, As, 256, mb, Q, 0, wn * 64);
    epi_H32(acc, P, b2, wn * 64, mb, lane);
  }
  __syncthreads();
  { // stage 5: t3 = h2 @ W3  [M128 N128 K256] -> Q rows 0..127
    f32x16 acc[2];
    gemm32n1<16, false>(acc, P, 512, mb, W3T, 256, wn * 32);
    epi_T32n1(acc, Q, wn * 32, mb, lane);
  }
  __syncthreads();
  { // stage 6: k = A @ t3 + b3 [M128 N128 K128] + fused RK epilogue
    f32x16 acc[2];
    gemm32n1<8, true>(acc, As, 256, mb, Q, 0, wn * 32);
    const int c = wn * 32 + l31;
    const float bb = b3[c];
    const int cz = c << 1;
#pragma unroll
    for (int mt = 0; mt < 2; ++mt) {
      f32x4 ya[4], ba[4];
#pragma unroll
      for (int q = 0; q < 4; ++q) ya[q] = SA[(mt * 4 + q) * 512 + tid];
      if constexpr (E == 2 || E == 3) {
#pragma unroll
        for (int q = 0; q < 4; ++q) ba[q] = SB[(mt * 4 + q) * 512 + tid];
      }
#pragma unroll
      for (int q = 0; q < 4; ++q) {
        const int r0 = mb + mt * 32 + (lh << 2) + (q << 3);
        const int i4 = mt * 4 + q;
        f32x4 wa, wb, zv;
#pragma unroll
        for (int j = 0; j < 4; ++j) {
          const int r = r0 + j;
          const float kv = acc[mt][4 * q + j] + bb;
          float z;
          if constexpr (E == 1) {
            wb[j] = kv;                                   // k1 -> SB
            z = ya[q][j] + (DT_ * (1.0f / 3.0f)) * kv;
          } else if constexpr (E == 2) {
            const float k1 = ba[q][j];
            const float y = ya[q][j];
            z = y + DT_ * (kv - k1 * (1.0f / 3.0f));
            wb[j] = y + DT_ * (k1 - kv);                  // U -> SB
            wa[j] = y + (DT_ * 0.125f) * (k1 + 3.0f * kv);  // V -> SA
          } else if constexpr (E == 3) {
            z = ba[q][j] + DT_ * kv;                      // z4 = U + dt*k3
            wa[j] = ya[q][j] + (DT_ * 0.375f) * kv;       // W -> SA
          } else {
            const float yn = ya[q][j] + (DT_ * 0.125f) * kv;
            wa[j] = yn;                                   // yn -> SA
            __builtin_nontemporal_store(yn, &out[batch * 163840 + r * 1280 + (step + 1) * 128 + c]);
            z = yn;
          }
          zv[j] = z;
        }
        const u32 z01 = cvtpk(zv.x, zv.y);
        const u32 z23 = cvtpk(zv.z, zv.w);
        *(u16*)((char*)P + (r0 + 0) * 256 + (cz ^ (((r0 + 0) & 7) << 4))) = (u16)z01;
        *(u16*)((char*)P + (r0 + 1) * 256 + (cz ^ (((r0 + 1) & 7) << 4))) = (u16)(z01 >> 16);
        *(u16*)((char*)P + (r0 + 2) * 256 + (cz ^ (((r0 + 2) & 7) << 4))) = (u16)z23;
        *(u16*)((char*)P + (r0 + 3) * 256 + (cz ^ (((r0 + 3) & 7) << 4))) = (u16)(z23 >> 16);
        if constexpr (E == 1 || E == 2) SB[i4 * 512 + tid] = wb;
        if constexpr (E != 1) SA[i4 * 512 + tid] = wa;
      }
    }
  }
  __syncthreads();
}

__global__ __launch_bounds__(512, 2)  // 8-wave block, 1 block/CU -> 2 waves/EU
void ode_main(
    const u16* __restrict__ Aswz,
    const u16* __restrict__ W1T, const u16* __restrict__ W2T, const u16* __restrict__ W3T,
    const float* __restrict__ b1, const float* __restrict__ b2, const float* __restrict__ b3,
    const float* __restrict__ x,
    f32x4* __restrict__ KS,
    float* __restrict__ out) {
  __shared__ u16 P[32768];   // 64 KB: activations node-major / z
  __shared__ u16 Q[32768];   // 64 KB: transposed intermediates t^T
  __shared__ u16 As[16384];  // 32 KB: normalized adjacency, pre-swizzled
  const int tid = threadIdx.x;
  const int lane = tid & 63;
  const int wid = tid >> 6;
  const int wm = wid >> 2, wn = wid & 3;
  const int mb = wm * 64;
  const int l31 = lane & 31, lh = lane >> 5;
  const int batch = blockIdx.x;
  f32x4* SA = KS + batch * 8192;       // 64 KB slab: y / V / W / yn
  f32x4* SB = SA + 4096;               // 64 KB slab: k1 / U

  { // stage adjacency into LDS (pre-swizzled in ws -> linear copy); 2048 uint4
    const uint4* s = (const uint4*)Aswz;
    uint4* d = (uint4*)As;
#pragma unroll
    for (int i = 0; i < 4; ++i) d[tid + i * 512] = s[tid + i * 512];
  }

  // init: y0 -> SA slab; seed z into P; write out step-0 slot. No persistent regs.
  // Thread->(r,c) map mirrors the stage-6 epilogue (32x32 D-layout).
#pragma unroll 1
  for (int mt = 0; mt < 2; ++mt)
#pragma unroll 1
    for (int q = 0; q < 4; ++q) {
      const int c = wn * 32 + l31;
      f32x4 w;
#pragma unroll
      for (int j = 0; j < 4; ++j) {
        const int r = mb + mt * 32 + (lh << 2) + (q << 3) + j;
        const float v = x[((batch * 128 + r) * 12 + 11) * 128 + c];
        w[j] = v;
        __builtin_nontemporal_store(v, &out[batch * 163840 + r * 1280 + c]);
        *(u16*)((char*)P + r * 256 + ((c << 1) ^ ((r & 7) << 4))) = f2bf(v);
      }
      SA[(mt * 4 + q) * 512 + tid] = w;
    }
  __syncthreads();

  for (int s = 0; s < 9; ++s) {
    feval<1>(s, P, Q, As, W1T, W2T, W3T, b1, b2, b3, SA, SB, out, batch, tid, lane, mb, wn);
    feval<2>(s, P, Q, As, W1T, W2T, W3T, b1, b2, b3, SA, SB, out, batch, tid, lane, mb, wn);
    feval<3>(s, P, Q, As, W1T, W2T, W3T, b1, b2, b3, SA, SB, out, batch, tid, lane, mb, wn);
    feval<4>(s, P, Q, As, W1T, W2T, W3T, b1, b2, b3, SA, SB, out, batch, tid, lane, mb, wn);
  }
}

// ---- prep kernels ----

__global__ void prep_adj_k(const float* __restrict__ adjw, u16* __restrict__ Aswz) {
  const int n = blockIdx.x;
  const int m = threadIdx.x;  // 128 threads = 2 waves
  const float w = adjw[n * 128 + m];
  const float sg = 1.0f / (1.0f + __expf(-w));
  float s = sg;
#pragma unroll
  for (int o = 1; o < 64; o <<= 1) s += __shfl_xor(s, o);
  __shared__ float red[2];
  if ((m & 63) == 0) red[m >> 6] = s;
  __syncthreads();
  const float deg = fmaxf(red[0] + red[1], 1.0f);
  const float v = sg / deg;
  *(u16*)((char*)Aswz + n * 256 + ((m << 1) ^ ((n & 7) << 4))) = f2bf(v);
}

__global__ void prep_w_k(const float* __restrict__ W1, const float* __restrict__ W2,
                         const float* __restrict__ W3,
                         u16* __restrict__ W1T, u16* __restrict__ W2T, u16* __restrict__ W3T) {
  const int i = blockIdx.x * 256 + threadIdx.x;
  if (i < 32768) {
    W1T[i] = f2bf(W1[(i & 127) * 256 + (i >> 7)]);  // W1T[hid][f] = W1[f][hid]
    W3T[i] = f2bf(W3[(i & 255) * 128 + (i >> 8)]);  // W3T[f][hid] = W3[hid][f]
  }
  if (i < 65536) W2T[i] = f2bf(W2[(i & 255) * 256 + (i >> 8)]);  // W2T[h2][h1] = W2[h1][h2]
}

extern "C" void kernel_launch(void* const* d_in, const int* in_sizes, int n_in,
                              void* d_out, int out_size, void* d_ws, size_t ws_size,
                              hipStream_t stream) {
  const float* x    = (const float*)d_in[0];
  const float* adjw = (const float*)d_in[1];
  const float* W1   = (const float*)d_in[2];
  const float* b1   = (const float*)d_in[3];
  const float* W2   = (const float*)d_in[4];
  const float* b2   = (const float*)d_in[5];
  const float* W3   = (const float*)d_in[6];
  const float* b3   = (const float*)d_in[7];
  float* out = (float*)d_out;

  u16* Aswz = (u16*)d_ws;
  u16* W1T = Aswz + 16384;
  u16* W2T = W1T + 32768;
  u16* W3T = W2T + 65536;
  f32x4* KS = (f32x4*)(W3T + 32768);  // 128 blocks x 128 KB = 16 MB RK state slabs

  prep_adj_k<<<128, 128, 0, stream>>>(adjw, Aswz);
  prep_w_k<<<256, 256, 0, stream>>>(W1, W2, W3, W1T, W2T, W3T);
  ode_main<<<128, 512, 0, stream>>>(Aswz, W1T, W2T, W3T, b1, b2, b3, x, KS, out);
}

// Round 18
// 942.481 us; speedup vs baseline: 1.2333x; 1.2333x over previous
//
#include <hip/hip_runtime.h>
#include <hip/hip_bf16.h>

typedef __attribute__((ext_vector_type(8))) short bf16x8;
typedef __attribute__((ext_vector_type(4))) float f32x4;
typedef unsigned short u16;
typedef unsigned int u32;

#define DT_ (10.0f / 9.0f)

__device__ __forceinline__ u16 f2bf(float f) {
  u32 u = __float_as_uint(f);
  u = (u + 0x7FFFu + ((u >> 16) & 1u)) >> 16;
  return (u16)u;
}

// Packed RNE f32x2 -> bf16x2 (one v_cvt_pk_bf16_f32).
__device__ __forceinline__ u32 cvtpk(float lo, float hi) {
  __hip_bfloat162 h = __float22bfloat162_rn(float2{lo, hi});
  return *reinterpret_cast<u32*>(&h);
}

__device__ __forceinline__ float tanh_fast(float x) {
  float ax = fabsf(x);
  float e = __expf(-2.0f * ax);
  float t = (1.0f - e) * __builtin_amdgcn_rcpf(1.0f + e);
  return copysignf(t, x);
}

// A/B fragment read from LDS: row-major [rows][K], row stride strideB bytes,
// XOR-swizzled with ((row&7)<<4).
__device__ __forceinline__ bf16x8 frag_lds(const u16* Mb, int row0, int kE, int strideB) {
  const int l = threadIdx.x & 63;
  const int r = row0 + (l & 15);
  const int kb = (kE + ((l >> 4) << 3)) << 1;
  const int off = r * strideB + (kb ^ ((r & 7) << 4));
  return *(const bf16x8*)((const char*)Mb + off);
}

// B-operand fragment straight from global W^T (row-major [N][K], bf16).
__device__ __forceinline__ bf16x8 frag_glb(const u16* WT, int col0, int kE, int K) {
  const int l = threadIdx.x & 63;
  const int j = col0 + (l & 15);
  const int k = kE + ((l >> 4) << 3);
  return *(const bf16x8*)(WT + j * K + k);
}

// Two-column-block pass, 2-deep software pipeline (R15/R16). Outer loop unroll-1
// (R11 lesson: full unroll hoists all loads and spills past the 128-VGPR grant).
template <int KST, bool BLDS>
__device__ __forceinline__ void gemm2(f32x4 (&acc)[4][2], const u16* Ab, int aStrideB, int mb,
                                      const u16* Bp, int bK, int nb) {
#pragma unroll
  for (int mt = 0; mt < 4; ++mt)
#pragma unroll
    for (int nt = 0; nt < 2; ++nt) acc[mt][nt] = (f32x4){0.f, 0.f, 0.f, 0.f};
  bf16x8 av0[4], bv0[2], av1[4], bv1[2];
#pragma unroll
  for (int nt = 0; nt < 2; ++nt) {
    if constexpr (BLDS) bv0[nt] = frag_lds(Bp, nb + nt * 16, 0, 256);
    else                bv0[nt] = frag_glb(Bp, nb + nt * 16, 0, bK);
  }
#pragma unroll
  for (int mt = 0; mt < 4; ++mt) av0[mt] = frag_lds(Ab, mb + mt * 16, 0, aStrideB);
#pragma unroll 1
  for (int ks = 0; ks < KST; ks += 2) {
    const int k1 = (ks + 1) * 32;
#pragma unroll
    for (int nt = 0; nt < 2; ++nt) {
      if constexpr (BLDS) bv1[nt] = frag_lds(Bp, nb + nt * 16, k1, 256);
      else                bv1[nt] = frag_glb(Bp, nb + nt * 16, k1, bK);
    }
#pragma unroll
    for (int mt = 0; mt < 4; ++mt) av1[mt] = frag_lds(Ab, mb + mt * 16, k1, aStrideB);
#pragma unroll
    for (int nt = 0; nt < 2; ++nt)
#pragma unroll
      for (int mt = 0; mt < 4; ++mt)
        acc[mt][nt] = __builtin_amdgcn_mfma_f32_16x16x32_bf16(av0[mt], bv0[nt], acc[mt][nt], 0, 0, 0);
    if (ks + 2 < KST) {
      const int k2 = (ks + 2) * 32;
#pragma unroll
      for (int nt = 0; nt < 2; ++nt) {
        if constexpr (BLDS) bv0[nt] = frag_lds(Bp, nb + nt * 16, k2, 256);
        else                bv0[nt] = frag_glb(Bp, nb + nt * 16, k2, bK);
      }
#pragma unroll
      for (int mt = 0; mt < 4; ++mt) av0[mt] = frag_lds(Ab, mb + mt * 16, k2, aStrideB);
    }
#pragma unroll
    for (int nt = 0; nt < 2; ++nt)
#pragma unroll
      for (int mt = 0; mt < 4; ++mt)
        acc[mt][nt] = __builtin_amdgcn_mfma_f32_16x16x32_bf16(av1[mt], bv1[nt], acc[mt][nt], 0, 0, 0);
  }
}

// Single-column-block pass (stage 6), same 2-deep pipeline.
template <int KST, bool BLDS>
__device__ __forceinline__ void gemm1(f32x4 (&acc)[4], const u16* Ab, int aStrideB, int mb,
                                      const u16* Bp, int bK, int nb) {
#pragma unroll
  for (int mt = 0; mt < 4; ++mt) acc[mt] = (f32x4){0.f, 0.f, 0.f, 0.f};
  bf16x8 av0[4], av1[4];
  bf16x8 bv0, bv1;
  if constexpr (BLDS) bv0 = frag_lds(Bp, nb, 0, 256);
  else                bv0 = frag_glb(Bp, nb, 0, bK);
#pragma unroll
  for (int mt = 0; mt < 4; ++mt) av0[mt] = frag_lds(Ab, mb + mt * 16, 0, aStrideB);
#pragma unroll 1
  for (int ks = 0; ks < KST; ks += 2) {
    const int k1 = (ks + 1) * 32;
    if constexpr (BLDS) bv1 = frag_lds(Bp, nb, k1, 256);
    else                bv1 = frag_glb(Bp, nb, k1, bK);
#pragma unroll
    for (int mt = 0; mt < 4; ++mt) av1[mt] = frag_lds(Ab, mb + mt * 16, k1, aStrideB);
#pragma unroll
    for (int mt = 0; mt < 4; ++mt)
      acc[mt] = __builtin_amdgcn_mfma_f32_16x16x32_bf16(av0[mt], bv0, acc[mt], 0, 0, 0);
    if (ks + 2 < KST) {
      const int k2 = (ks + 2) * 32;
      if constexpr (BLDS) bv0 = frag_lds(Bp, nb, k2, 256);
      else                bv0 = frag_glb(Bp, nb, k2, bK);
#pragma unroll
      for (int mt = 0; mt < 4; ++mt) av0[mt] = frag_lds(Ab, mb + mt * 16, k2, aStrideB);
    }
#pragma unroll
    for (int mt = 0; mt < 4; ++mt)
      acc[mt] = __builtin_amdgcn_mfma_f32_16x16x32_bf16(av1[mt], bv1, acc[mt], 0, 0, 0);
  }
}

// Write acc[4][2] transposed (t^T) into Q: packed cvt_pk conversions + uint2 stores.
__device__ __forceinline__ void epi_T2(const f32x4 (&acc)[4][2], u16* Q, int nb, int mb, int lane) {
  const int l15 = lane & 15, lg = lane >> 4;
#pragma unroll
  for (int nt = 0; nt < 2; ++nt) {
    const int c = nb + nt * 16 + l15;
    const int swz = (c & 7) << 4;
    char* rowp = (char*)Q + c * 256;
#pragma unroll
    for (int mt = 0; mt < 4; ++mt) {
      f32x4 v = acc[mt][nt];
      const int r0 = mb + mt * 16 + (lg << 2);
      uint2 pk;
      pk.x = cvtpk(v.x, v.y);
      pk.y = cvtpk(v.z, v.w);
      *(uint2*)(rowp + ((r0 << 1) ^ swz)) = pk;
    }
  }
}

// Node-major write (no bias/activation): Az -> Q-lo, stride 256B, swizzled.
__device__ __forceinline__ void epi_N2(const f32x4 (&acc)[4][2], u16* Qlo, int nb, int mb, int lane) {
  const int l15 = lane & 15, lg = lane >> 4;
#pragma unroll
  for (int nt = 0; nt < 2; ++nt) {
    const int c = nb + nt * 16 + l15;
    const int csh = c << 1;
#pragma unroll
    for (int mt = 0; mt < 4; ++mt) {
      f32x4 v = acc[mt][nt];
      const int r0 = mb + mt * 16 + (lg << 2);
      const u32 p01 = cvtpk(v.x, v.y);
      const u32 p23 = cvtpk(v.z, v.w);
      *(u16*)((char*)Qlo + (r0 + 0) * 256 + (csh ^ (((r0 + 0) & 7) << 4))) = (u16)p01;
      *(u16*)((char*)Qlo + (r0 + 1) * 256 + (csh ^ (((r0 + 1) & 7) << 4))) = (u16)(p01 >> 16);
      *(u16*)((char*)Qlo + (r0 + 2) * 256 + (csh ^ (((r0 + 2) & 7) << 4))) = (u16)p23;
      *(u16*)((char*)Qlo + (r0 + 3) * 256 + (csh ^ (((r0 + 3) & 7) << 4))) = (u16)(p23 >> 16);
    }
  }
}

// Bias + tanh + node-major P write (stride 512B, swizzled).
__device__ __forceinline__ void epi_H2(const f32x4 (&acc)[4][2], u16* P, const float* __restrict__ b,
                                       int nb, int mb, int lane) {
  const int l15 = lane & 15, lg = lane >> 4;
#pragma unroll
  for (int nt = 0; nt < 2; ++nt) {
    const int c = nb + nt * 16 + l15;
    const float bb = b[c];
    const int csh = c << 1;
#pragma unroll
    for (int mt = 0; mt < 4; ++mt) {
      f32x4 v = acc[mt][nt];
      const int r0 = mb + mt * 16 + (lg << 2);
      float t0 = tanh_fast(v.x + bb), t1 = tanh_fast(v.y + bb);
      float t2 = tanh_fast(v.z + bb), t3 = tanh_fast(v.w + bb);
      const u32 p01 = cvtpk(t0, t1);
      const u32 p23 = cvtpk(t2, t3);
      *(u16*)((char*)P + (r0 + 0) * 512 + (csh ^ (((r0 + 0) & 7) << 4))) = (u16)p01;
      *(u16*)((char*)P + (r0 + 1) * 512 + (csh ^ (((r0 + 1) & 7) << 4))) = (u16)(p01 >> 16);
      *(u16*)((char*)P + (r0 + 2) * 512 + (csh ^ (((r0 + 2) & 7) << 4))) = (u16)p23;
      *(u16*)((char*)P + (r0 + 3) * 512 + (csh ^ (((r0 + 3) & 7) << 4))) = (u16)(p23 >> 16);
    }
  }
}

// One f(z) evaluation. Reassociated layer 1: Az = A@z FIRST (all-LDS, half FLOPs),
// then h1 = tanh(Az@W1+b1). z lives TRANSPOSED (z^T) in Q-hi; Az node-major in Q-lo;
// h1/h2 node-major in P (stride 512); t2^T full Q; t3^T Q-lo.
// ZERO persistent register state. RK state in ws slabs: SA: y->V->W->yn, SB: k1->U.
template <int E>
__device__ __forceinline__ void feval(int step,
    u16* P, u16* Q, const u16* As,
    const u16* __restrict__ W1T, const u16* __restrict__ W2T, const u16* __restrict__ W3T,
    const float* __restrict__ b1, const float* __restrict__ b2, const float* __restrict__ b3,
    f32x4* __restrict__ SA, f32x4* __restrict__ SB,
    float* __restrict__ out,
    int batch, int tid, int lane, int mb, int wn) {
  const int l15 = lane & 15, lg = lane >> 4;
  u16* Qhi = Q + 16384;  // z^T region (32 KB)

  { // stage 1: Az = A @ z   [M128 N128 K128], ALL-LDS -> Q-lo node-major
    f32x4 acc[4][2];
    gemm2<4, true>(acc, As, 256, mb, Qhi, 0, wn * 32);
    epi_N2(acc, Q, wn * 32, mb, lane);
  }
  __syncthreads();
  // stage 2: h1 = tanh(Az @ W1 + b1)  [M128 N256 K128] -> P node-major (stride 512)
#pragma unroll 1
  for (int h = 0; h < 2; ++h) {
    f32x4 acc[4][2];
    gemm2<4, false>(acc, Q, 256, mb, W1T, 128, wn * 64 + h * 32);
    epi_H2(acc, P, b1, wn * 64 + h * 32, mb, lane);
  }
  __syncthreads();
  // stage 3: t2 = h1 @ W2  [M128 N256 K256] -> Q full (t^T)
#pragma unroll 1
  for (int h = 0; h < 2; ++h) {
    f32x4 acc[4][2];
    gemm2<8, false>(acc, P, 512, mb, W2T, 256, wn * 64 + h * 32);
    epi_T2(acc, Q, wn * 64 + h * 32, mb, lane);
  }
  __syncthreads();
  // stage 4: h2 = tanh(A @ t2 + b2) -> P node-major
#pragma unroll 1
  for (int h = 0; h < 2; ++h) {
    f32x4 acc[4][2];
    gemm2<4, true>(acc, As, 256, mb, Q, 0, wn * 64 + h * 32);
    epi_H2(acc, P, b2, wn * 64 + h * 32, mb, lane);
  }
  __syncthreads();
  { // stage 5: t3 = h2 @ W3  [M128 N128 K256] -> Q-lo (t^T rows 0..127)
    f32x4 acc[4][2];
    gemm2<8, false>(acc, P, 512, mb, W3T, 256, wn * 32);
    epi_T2(acc, Q, wn * 32, mb, lane);
  }
  __syncthreads();

  // stage 6: k = A @ t3 + b3 [M128 N128 K128] + fused RK epilogue; z^T -> Q-hi (uint2)
#pragma unroll 1
  for (int p = 0; p < 2; ++p) {
    f32x4 ya[4], ba[4];
#pragma unroll
    for (int q = 0; q < 4; ++q) ya[q] = SA[(p * 4 + q) * 512 + tid];
    if constexpr (E == 2 || E == 3) {
#pragma unroll
      for (int q = 0; q < 4; ++q) ba[q] = SB[(p * 4 + q) * 512 + tid];
    }
    f32x4 acc[4];
    gemm1<4, true>(acc, As, 256, mb, Q, 0, wn * 32 + p * 16);
    const int c = wn * 32 + p * 16 + l15;
    const float bb = b3[c];
    const int swz = (c & 7) << 4;
    char* zrow = (char*)Qhi + c * 256;
#pragma unroll
    for (int mt = 0; mt < 4; ++mt) {
      f32x4 v = acc[mt];
      const int r0 = mb + mt * 16 + (lg << 2);
      const int i4 = p * 4 + mt;
      f32x4 wa, wb, zv;
#pragma unroll
      for (int e = 0; e < 4; ++e) {
        const int r = r0 + e;
        const float kv = v[e] + bb;
        float z;
        if constexpr (E == 1) {
          wb[e] = kv;                                   // k1 -> SB
          z = ya[mt][e] + (DT_ * (1.0f / 3.0f)) * kv;
        } else if constexpr (E == 2) {
          const float k1 = ba[mt][e];
          const float y = ya[mt][e];
          z = y + DT_ * (kv - k1 * (1.0f / 3.0f));
          wb[e] = y + DT_ * (k1 - kv);                  // U -> SB
          wa[e] = y + (DT_ * 0.125f) * (k1 + 3.0f * kv);  // V -> SA
        } else if constexpr (E == 3) {
          z = ba[mt][e] + DT_ * kv;                     // z4 = U + dt*k3
          wa[e] = ya[mt][e] + (DT_ * 0.375f) * kv;      // W -> SA
        } else {
          const float yn = ya[mt][e] + (DT_ * 0.125f) * kv;
          wa[e] = yn;                                   // yn -> SA
          __builtin_nontemporal_store(yn, &out[batch * 163840 + r * 1280 + (step + 1) * 128 + c]);
          z = yn;
        }
        zv[e] = z;
      }
      uint2 pk;
      pk.x = cvtpk(zv.x, zv.y);
      pk.y = cvtpk(zv.z, zv.w);
      *(uint2*)(zrow + ((r0 << 1) ^ swz)) = pk;         // z^T, contiguous 8B
      if constexpr (E == 1 || E == 2) SB[i4 * 512 + tid] = wb;
      if constexpr (E != 1) SA[i4 * 512 + tid] = wa;
    }
  }
  __syncthreads();
}

__global__ __launch_bounds__(512, 2)  // 8-wave block, 1 block/CU -> 2 waves/EU
void ode_main(
    const u16* __restrict__ Aswz,
    const u16* __restrict__ W1T, const u16* __restrict__ W2T, const u16* __restrict__ W3T,
    const float* __restrict__ b1, const float* __restrict__ b2, const float* __restrict__ b3,
    const float* __restrict__ x,
    f32x4* __restrict__ KS,
    float* __restrict__ out) {
  __shared__ u16 P[32768];   // 64 KB: h1/h2 node-major (stride 512)
  __shared__ u16 Q[32768];   // 64 KB: lo = Az / t^T; hi = z^T
  __shared__ u16 As[16384];  // 32 KB: normalized adjacency, pre-swizzled
  const int tid = threadIdx.x;
  const int lane = tid & 63;
  const int wid = tid >> 6;
  const int wm = wid >> 2, wn = wid & 3;
  const int mb = wm * 64;
  const int l15 = lane & 15, lg = lane >> 4;
  const int batch = blockIdx.x;
  f32x4* SA = KS + batch * 8192;       // 64 KB slab: y / V / W / yn
  f32x4* SB = SA + 4096;               // 64 KB slab: k1 / U
  u16* Qhi = Q + 16384;

  { // stage adjacency into LDS (pre-swizzled in ws -> linear copy); 2048 uint4
    const uint4* s = (const uint4*)Aswz;
    uint4* d = (uint4*)As;
#pragma unroll
    for (int i = 0; i < 4; ++i) d[tid + i * 512] = s[tid + i * 512];
  }

  // init: y0 -> SA slab; seed z^T into Q-hi (uint2); write out step-0 slot.
#pragma unroll 1
  for (int p = 0; p < 2; ++p)
#pragma unroll 1
    for (int mt = 0; mt < 4; ++mt) {
      const int c = wn * 32 + p * 16 + l15;
      const int r0 = mb + mt * 16 + (lg << 2);
      f32x4 w;
#pragma unroll
      for (int e = 0; e < 4; ++e) {
        const int r = r0 + e;
        const float v = x[((batch * 128 + r) * 12 + 11) * 128 + c];
        w[e] = v;
        __builtin_nontemporal_store(v, &out[batch * 163840 + r * 1280 + c]);
      }
      uint2 pk;
      pk.x = cvtpk(w.x, w.y);
      pk.y = cvtpk(w.z, w.w);
      *(uint2*)((char*)Qhi + c * 256 + ((r0 << 1) ^ ((c & 7) << 4))) = pk;
      SA[(p * 4 + mt) * 512 + tid] = w;
    }
  __syncthreads();

  for (int s = 0; s < 9; ++s) {
    feval<1>(s, P, Q, As, W1T, W2T, W3T, b1, b2, b3, SA, SB, out, batch, tid, lane, mb, wn);
    feval<2>(s, P, Q, As, W1T, W2T, W3T, b1, b2, b3, SA, SB, out, batch, tid, lane, mb, wn);
    feval<3>(s, P, Q, As, W1T, W2T, W3T, b1, b2, b3, SA, SB, out, batch, tid, lane, mb, wn);
    feval<4>(s, P, Q, As, W1T, W2T, W3T, b1, b2, b3, SA, SB, out, batch, tid, lane, mb, wn);
  }
}

// ---- prep kernels ----

__global__ void prep_adj_k(const float* __restrict__ adjw, u16* __restrict__ Aswz) {
  const int n = blockIdx.x;
  const int m = threadIdx.x;  // 128 threads = 2 waves
  const float w = adjw[n * 128 + m];
  const float sg = 1.0f / (1.0f + __expf(-w));
  float s = sg;
#pragma unroll
  for (int o = 1; o < 64; o <<= 1) s += __shfl_xor(s, o);
  __shared__ float red[2];
  if ((m & 63) == 0) red[m >> 6] = s;
  __syncthreads();
  const float deg = fmaxf(red[0] + red[1], 1.0f);
  const float v = sg / deg;
  *(u16*)((char*)Aswz + n * 256 + ((m << 1) ^ ((n & 7) << 4))) = f2bf(v);
}

__global__ void prep_w_k(const float* __restrict__ W1, const float* __restrict__ W2,
                         const float* __restrict__ W3,
                         u16* __restrict__ W1T, u16* __restrict__ W2T, u16* __restrict__ W3T) {
  const int i = blockIdx.x * 256 + threadIdx.x;
  if (i < 32768) {
    W1T[i] = f2bf(W1[(i & 127) * 256 + (i >> 7)]);  // W1T[hid][f] = W1[f][hid]
    W3T[i] = f2bf(W3[(i & 255) * 128 + (i >> 8)]);  // W3T[f][hid] = W3[hid][f]
  }
  if (i < 65536) W2T[i] = f2bf(W2[(i & 255) * 256 + (i >> 8)]);  // W2T[h2][h1] = W2[h1][h2]
}

extern "C" void kernel_launch(void* const* d_in, const int* in_sizes, int n_in,
                              void* d_out, int out_size, void* d_ws, size_t ws_size,
                              hipStream_t stream) {
  const float* x    = (const float*)d_in[0];
  const float* adjw = (const float*)d_in[1];
  const float* W1   = (const float*)d_in[2];
  const float* b1   = (const float*)d_in[3];
  const float* W2   = (const float*)d_in[4];
  const float* b2   = (const float*)d_in[5];
  const float* W3   = (const float*)d_in[6];
  const float* b3   = (const float*)d_in[7];
  float* out = (float*)d_out;

  u16* Aswz = (u16*)d_ws;
  u16* W1T = Aswz + 16384;
  u16* W2T = W1T + 32768;
  u16* W3T = W2T + 65536;
  f32x4* KS = (f32x4*)(W3T + 32768);  // 128 blocks x 128 KB = 16 MB RK state slabs

  prep_adj_k<<<128, 128, 0, stream>>>(adjw, Aswz);
  prep_w_k<<<256, 256, 0, stream>>>(W1, W2, W3, W1T, W2T, W3T);
  ode_main<<<128, 512, 0, stream>>>(Aswz, W1T, W2T, W3T, b1, b2, b3, x, KS, out);
}